// Round 1
// baseline (384.600 us; speedup 1.0000x reference)
//
#include <hip/hip_runtime.h>

typedef _Float16 half_t;
typedef _Float16 half8 __attribute__((ext_vector_type(8)));
typedef float floatx4 __attribute__((ext_vector_type(4)));

#define HST 264            // LDS row stride in halves: 256 + 8 pad (16B, odd multiple of 16B)
#define B_ 32
#define T_ 512
#define H_ 256
#define L_ 2048

// ------------------------------------------------------------------
// Weight prep: fp32 [pred][layer][k][n] -> f16 MFMA-B-fragment layout.
// Frag id t = ((pred*4+layer)*8 + kk)*16 + nt ; lane l holds 8 halves:
//   W[kk*32 + (l>>4)*8 + j][nt*16 + (l&15)]
// ------------------------------------------------------------------
__global__ void prep_weights_kernel(const float* __restrict__ dur_W,
                                    const float* __restrict__ pit_W,
                                    const float* __restrict__ en_W,
                                    half_t* __restrict__ Wp) {
  int g = blockIdx.x * 256 + threadIdx.x;   // [0, 98304)
  int lane = g & 63;
  int t = g >> 6;                           // [0, 1536)
  int nt = t & 15;
  int kk = (t >> 4) & 7;
  int layer = (t >> 7) & 3;
  int pred = t >> 9;
  const float* W = (pred == 0 ? dur_W : (pred == 1 ? pit_W : en_W)) + layer * 65536;
  int n = nt * 16 + (lane & 15);
  int k0 = kk * 32 + (lane >> 4) * 8;
  half8 o;
#pragma unroll
  for (int j = 0; j < 8; ++j) o[j] = (half_t)W[(k0 + j) * 256 + n];
  *(half8*)&Wp[(size_t)t * 512 + lane * 8] = o;
}

// ------------------------------------------------------------------
// Per-batch cumsum of duration_target; mel_len = min(cum[-1], L).
// One block (64 lanes) per batch: lane loads 8, wave-scan via shfl_up.
// ------------------------------------------------------------------
__global__ void scan_kernel(const int* __restrict__ dur,
                            int* __restrict__ cum,
                            int* __restrict__ ml_ws,
                            float* __restrict__ out4) {
  int b = blockIdx.x;
  int l = threadIdx.x;
  const int* dr = dur + b * T_;
  int v[8];
  int base = l * 8;
#pragma unroll
  for (int j = 0; j < 8; ++j) v[j] = dr[base + j];
#pragma unroll
  for (int j = 1; j < 8; ++j) v[j] += v[j - 1];
  int tot = v[7];
  int inc = tot;
  for (int d = 1; d < 64; d <<= 1) {
    int t = __shfl_up(inc, d);
    if (l >= d) inc += t;
  }
  int excl = inc - tot;
  int* cr = cum + b * T_;
#pragma unroll
  for (int j = 0; j < 8; ++j) cr[base + j] = excl + v[j];
  if (l == 63) {
    int mel = min(inc, L_);
    ml_ws[b] = mel;
    out4[b] = (float)mel;
  }
}

// ------------------------------------------------------------------
// Length regulator: searchsorted(cum, m, 'right'), writes idx (ws),
// mel_mask (out5, as 0.0/1.0), and out0 = xe + pitch_emb + energy_emb.
// Grid: 32 batches x 16 chunks of 128 frames. Block 256.
// ------------------------------------------------------------------
__global__ void regulate_kernel(const float* __restrict__ x,
                                const float* __restrict__ pitch_t,
                                const float* __restrict__ energy_t,
                                const float* __restrict__ pemb,
                                const float* __restrict__ eemb,
                                const int* __restrict__ cum,
                                const int* __restrict__ mlw,
                                int* __restrict__ idx_ws,
                                float* __restrict__ out0,
                                float* __restrict__ out5) {
  __shared__ int cum_l[T_];
  __shared__ int idx_l[128];
  int tid = threadIdx.x;
  int b = blockIdx.x >> 4;
  int chunk = blockIdx.x & 15;
  for (int i = tid; i < T_; i += 256) cum_l[i] = cum[b * T_ + i];
  __syncthreads();
  int ml = mlw[b];
  if (tid < 128) {
    int m = chunk * 128 + tid;
    int lo = 0;
#pragma unroll
    for (int sh = 8; sh >= 0; --sh) {
      int c = lo + (1 << sh);
      if (c <= T_ && cum_l[c - 1] <= m) lo = c;
    }
    int idx = min(lo, T_ - 1);
    idx_l[tid] = idx;
    int g = b * L_ + m;
    idx_ws[g] = idx;
    out5[g] = (m >= ml) ? 1.0f : 0.0f;
  }
  __syncthreads();
  int wv = tid >> 6, lane = tid & 63;
  for (int it = 0; it < 32; ++it) {
    int p = wv * 32 + it;
    int m = chunk * 128 + p;
    int g = b * L_ + m;
    int ir = idx_l[p];
    float xv0 = 0.f, xv1 = 0.f, xv2 = 0.f, xv3 = 0.f;
    if (m < ml) {
      const float4 xv = *(const float4*)&x[((size_t)(b * T_ + ir)) * H_ + lane * 4];
      xv0 = xv.x; xv1 = xv.y; xv2 = xv.z; xv3 = xv.w;
    }
    int pi = (int)ceilf(pitch_t[g] * 256.0f);
    int ei = (int)ceilf(energy_t[g] * 256.0f);
    const float4 pv = *(const float4*)&pemb[(size_t)pi * H_ + lane * 4];
    const float4 ev = *(const float4*)&eemb[(size_t)ei * H_ + lane * 4];
    float4 o;
    o.x = xv0 + pv.x + ev.x;
    o.y = xv1 + pv.y + ev.y;
    o.z = xv2 + pv.z + ev.z;
    o.w = xv3 + pv.w + ev.w;
    *(float4*)&out0[(size_t)g * H_ + lane * 4] = o;
  }
}

// ------------------------------------------------------------------
// Fused 4-layer MLP + head. Block = 256 threads (4 waves), 128 rows.
// Each wave owns 32 rows (2 MFMA row-tiles) -> NO __syncthreads at all:
// h kept in LDS between layers; wave only reads/writes its own rows.
// mode: 0 = duration (input = x rows direct, tanh epilogue)
//       1 = pitch    (gather xe via idx, relu epilogue)
//       2 = energy   (gather xe via idx, plain epilogue)
// ------------------------------------------------------------------
__global__ void predictor_kernel(const float* __restrict__ xin,
                                 const half_t* __restrict__ Wp,  // this pred's swizzled weights
                                 const float* __restrict__ bias, // [4,256]
                                 const float* __restrict__ w_head,
                                 const float* __restrict__ b2,
                                 const int* __restrict__ idx_ws,
                                 const int* __restrict__ mlw,
                                 const float* __restrict__ src_seq,
                                 const unsigned char* __restrict__ src_mask,
                                 float* __restrict__ outp,
                                 int mode) {
  __shared__ half_t hlds[128 * HST];
  int tid = threadIdx.x;
  int wv = tid >> 6, lane = tid & 63;
  int mi = lane & 15, qi = lane >> 4;
  int wrow0 = wv * 32;
  int brow0 = blockIdx.x * 128;

  // ---- stage input rows (f16) into LDS; wave stages its own 32 rows ----
  if (mode == 0) {
    for (int it = 0; it < 32; ++it) {
      int row = brow0 + wrow0 + it;
      const float4 xv = *(const float4*)&xin[(size_t)row * H_ + lane * 4];
      half_t* dst = &hlds[(wrow0 + it) * HST + lane * 4];
      dst[0] = (half_t)xv.x; dst[1] = (half_t)xv.y;
      dst[2] = (half_t)xv.z; dst[3] = (half_t)xv.w;
    }
  } else {
    int b = brow0 >> 11;       // 2048 rows per batch, 128 | 2048
    int m0 = brow0 & (L_ - 1);
    int ml = mlw[b];
    for (int it = 0; it < 32; ++it) {
      int m = m0 + wrow0 + it;
      float x0 = 0.f, x1 = 0.f, x2 = 0.f, x3 = 0.f;
      if (m < ml) {
        int ir = idx_ws[b * L_ + m];
        const float4 xv = *(const float4*)&xin[((size_t)(b * T_ + ir)) * H_ + lane * 4];
        x0 = xv.x; x1 = xv.y; x2 = xv.z; x3 = xv.w;
      }
      half_t* dst = &hlds[(wrow0 + it) * HST + lane * 4];
      dst[0] = (half_t)x0; dst[1] = (half_t)x1;
      dst[2] = (half_t)x2; dst[3] = (half_t)x3;
    }
  }

  // ---- 4 layers: h = relu(h @ W + b), in-place per wave ----
  for (int layer = 0; layer < 4; ++layer) {
    half8 afr[2][8];
#pragma unroll
    for (int rt = 0; rt < 2; ++rt)
#pragma unroll
      for (int kk = 0; kk < 8; ++kk)
        afr[rt][kk] = *(const half8*)&hlds[(wrow0 + rt * 16 + mi) * HST + kk * 32 + qi * 8];
    const half_t* wl = Wp + (size_t)(layer * 128) * 512;
    const float* bl = bias + layer * 256;
#pragma unroll 2
    for (int nt = 0; nt < 16; ++nt) {
      half8 bfr[8];
#pragma unroll
      for (int kk = 0; kk < 8; ++kk)
        bfr[kk] = *(const half8*)&wl[(size_t)(kk * 16 + nt) * 512 + lane * 8];
      floatx4 acc0 = {0.f, 0.f, 0.f, 0.f};
      floatx4 acc1 = {0.f, 0.f, 0.f, 0.f};
#pragma unroll
      for (int kk = 0; kk < 8; ++kk) {
        acc0 = __builtin_amdgcn_mfma_f32_16x16x32_f16(afr[0][kk], bfr[kk], acc0, 0, 0, 0);
        acc1 = __builtin_amdgcn_mfma_f32_16x16x32_f16(afr[1][kk], bfr[kk], acc1, 0, 0, 0);
      }
      float bn = bl[nt * 16 + mi];
#pragma unroll
      for (int r = 0; r < 4; ++r) {
        float v0 = fmaxf(acc0[r] + bn, 0.f);
        float v1 = fmaxf(acc1[r] + bn, 0.f);
        hlds[(wrow0 + qi * 4 + r) * HST + nt * 16 + mi] = (half_t)v0;
        hlds[(wrow0 + 16 + qi * 4 + r) * HST + nt * 16 + mi] = (half_t)v1;
      }
    }
  }

  // ---- head: out = h . w + b2, then per-mode epilogue ----
  {
    int r = lane >> 1, hf = lane & 1;
    int lrow = wrow0 + r;
    float sum = 0.f;
    const half_t* hrow = &hlds[lrow * HST + hf * 128];
    const float* wh = w_head + hf * 128;
#pragma unroll
    for (int j = 0; j < 16; ++j) {
      half8 hv = *(const half8*)&hrow[j * 8];
#pragma unroll
      for (int u = 0; u < 8; ++u) sum += (float)hv[u] * wh[j * 8 + u];
    }
    sum += __shfl_xor(sum, 1);
    if (hf == 0) {
      int row = brow0 + lrow;
      float d = sum + b2[0];
      if (mode == 0) {
        if (src_mask[row]) d = 0.f;
        float s2 = src_seq[(size_t)row * 3 + 2];
        outp[row] = (tanhf(d) + 1.0f) * s2;
      } else {
        int b = row >> 11;
        int m = row & (L_ - 1);
        float v = (m >= mlw[b]) ? 0.f : d;
        outp[row] = (mode == 1) ? fmaxf(v, 0.f) : v;
      }
    }
  }
}

extern "C" void kernel_launch(void* const* d_in, const int* in_sizes, int n_in,
                              void* d_out, int out_size, void* d_ws, size_t ws_size,
                              hipStream_t stream) {
  const float* x        = (const float*)d_in[0];
  const float* src_seq  = (const float*)d_in[1];
  const int*   durt     = (const int*)d_in[2];
  const float* pitcht   = (const float*)d_in[3];
  const float* energyt  = (const float*)d_in[4];
  const unsigned char* src_mask = (const unsigned char*)d_in[5];
  const float* dur_W  = (const float*)d_in[7];
  const float* dur_b  = (const float*)d_in[8];
  const float* dur_w  = (const float*)d_in[9];
  const float* dur_b2 = (const float*)d_in[10];
  const float* pit_W  = (const float*)d_in[11];
  const float* pit_b  = (const float*)d_in[12];
  const float* pit_w  = (const float*)d_in[13];
  const float* pit_b2 = (const float*)d_in[14];
  const float* en_W   = (const float*)d_in[15];
  const float* en_b   = (const float*)d_in[16];
  const float* en_w   = (const float*)d_in[17];
  const float* en_b2  = (const float*)d_in[18];
  const float* pemb   = (const float*)d_in[19];
  const float* eemb   = (const float*)d_in[20];

  float* out0 = (float*)d_out;              // [32,2048,256]
  float* out1 = out0 + 16777216;            // [32,512]   log_duration
  float* out2 = out1 + 16384;               // [32,2048]  pitch_prediction
  float* out3 = out2 + 65536;               // [32,2048]  energy_prediction
  float* out4 = out3 + 65536;               // [32]       mel_len (as float)
  float* out5 = out4 + 32;                  // [32,2048]  mel_mask (0/1 float)

  int* idx_ws = (int*)d_ws;                 // 65536 ints
  int* cum_ws = idx_ws + 65536;             // 16384 ints
  int* ml_ws  = cum_ws + 16384;             // 32 ints
  half_t* Wp  = (half_t*)((char*)d_ws + 327808);  // 3*262144 halves, 16B aligned

  prep_weights_kernel<<<dim3(384), dim3(256), 0, stream>>>(dur_W, pit_W, en_W, Wp);
  scan_kernel<<<dim3(32), dim3(64), 0, stream>>>(durt, cum_ws, ml_ws, out4);
  regulate_kernel<<<dim3(512), dim3(256), 0, stream>>>(x, pitcht, energyt, pemb, eemb,
                                                       cum_ws, ml_ws, idx_ws, out0, out5);
  predictor_kernel<<<dim3(128), dim3(256), 0, stream>>>(x, Wp, dur_b, dur_w, dur_b2,
                                                        nullptr, nullptr, src_seq, src_mask,
                                                        out1, 0);
  predictor_kernel<<<dim3(512), dim3(256), 0, stream>>>(x, Wp + 262144, pit_b, pit_w, pit_b2,
                                                        idx_ws, ml_ws, nullptr, nullptr,
                                                        out2, 1);
  predictor_kernel<<<dim3(512), dim3(256), 0, stream>>>(x, Wp + 524288, en_b, en_w, en_b2,
                                                        idx_ws, ml_ws, nullptr, nullptr,
                                                        out3, 2);
}

// Round 2
// 282.716 us; speedup vs baseline: 1.3604x; 1.3604x over previous
//
#include <hip/hip_runtime.h>

typedef _Float16 half_t;
typedef _Float16 half8 __attribute__((ext_vector_type(8)));
typedef float floatx4 __attribute__((ext_vector_type(4)));

#define HST 264            // LDS row stride in halves: 256 + 8 pad (16B, odd multiple of 16B)
#define B_ 32
#define T_ 512
#define H_ 256
#define L_ 2048

// ------------------------------------------------------------------
// Weight prep: fp32 [pred][layer][k][n] -> f16 MFMA-B-fragment layout.
// Frag id t = ((pred*4+layer)*8 + kk)*16 + nt ; lane l holds 8 halves:
//   W[kk*32 + (l>>4)*8 + j][nt*16 + (l&15)]
// ------------------------------------------------------------------
__global__ void prep_weights_kernel(const float* __restrict__ dur_W,
                                    const float* __restrict__ pit_W,
                                    const float* __restrict__ en_W,
                                    half_t* __restrict__ Wp) {
  int g = blockIdx.x * 256 + threadIdx.x;   // [0, 98304)
  int lane = g & 63;
  int t = g >> 6;                           // [0, 1536)
  int nt = t & 15;
  int kk = (t >> 4) & 7;
  int layer = (t >> 7) & 3;
  int pred = t >> 9;
  const float* W = (pred == 0 ? dur_W : (pred == 1 ? pit_W : en_W)) + layer * 65536;
  int n = nt * 16 + (lane & 15);
  int k0 = kk * 32 + (lane >> 4) * 8;
  half8 o;
#pragma unroll
  for (int j = 0; j < 8; ++j) o[j] = (half_t)W[(k0 + j) * 256 + n];
  *(half8*)&Wp[(size_t)t * 512 + lane * 8] = o;
}

// ------------------------------------------------------------------
// Length regulator (scan fused in): each block re-scans its batch's
// durations (wave 0), then searchsorted + gather + embedding add.
// Grid: 32 batches x 16 chunks of 128 frames. Block 256.
// ------------------------------------------------------------------
__global__ void regulate_kernel(const float* __restrict__ x,
                                const int* __restrict__ dur,
                                const float* __restrict__ pitch_t,
                                const float* __restrict__ energy_t,
                                const float* __restrict__ pemb,
                                const float* __restrict__ eemb,
                                int* __restrict__ idx_ws,
                                int* __restrict__ ml_ws,
                                float* __restrict__ out0,
                                float* __restrict__ out4,
                                float* __restrict__ out5) {
  __shared__ int cum_l[T_];
  __shared__ int idx_l[128];
  __shared__ int ml_s;
  int tid = threadIdx.x;
  int b = blockIdx.x >> 4;
  int chunk = blockIdx.x & 15;

  if (tid < 64) {
    int l = tid;
    const int* dr = dur + b * T_;
    int v[8];
    int base = l * 8;
#pragma unroll
    for (int j = 0; j < 8; ++j) v[j] = dr[base + j];
#pragma unroll
    for (int j = 1; j < 8; ++j) v[j] += v[j - 1];
    int tot = v[7];
    int inc = tot;
    for (int d = 1; d < 64; d <<= 1) {
      int t = __shfl_up(inc, d);
      if (l >= d) inc += t;
    }
    int excl = inc - tot;
#pragma unroll
    for (int j = 0; j < 8; ++j) cum_l[base + j] = excl + v[j];
    if (l == 63) {
      int mel = min(inc, L_);
      ml_s = mel;
      if (chunk == 0) {
        ml_ws[b] = mel;
        out4[b] = (float)mel;
      }
    }
  }
  __syncthreads();
  int ml = ml_s;
  if (tid < 128) {
    int m = chunk * 128 + tid;
    int lo = 0;
#pragma unroll
    for (int sh = 8; sh >= 0; --sh) {
      int c = lo + (1 << sh);
      if (c <= T_ && cum_l[c - 1] <= m) lo = c;
    }
    int idx = min(lo, T_ - 1);
    idx_l[tid] = idx;
    int g = b * L_ + m;
    idx_ws[g] = idx;
    out5[g] = (m >= ml) ? 1.0f : 0.0f;
  }
  __syncthreads();
  int wv = tid >> 6, lane = tid & 63;
  for (int it = 0; it < 32; ++it) {
    int p = wv * 32 + it;
    int m = chunk * 128 + p;
    int g = b * L_ + m;
    int ir = idx_l[p];
    float xv0 = 0.f, xv1 = 0.f, xv2 = 0.f, xv3 = 0.f;
    if (m < ml) {
      const float4 xv = *(const float4*)&x[((size_t)(b * T_ + ir)) * H_ + lane * 4];
      xv0 = xv.x; xv1 = xv.y; xv2 = xv.z; xv3 = xv.w;
    }
    int pi = (int)ceilf(pitch_t[g] * 256.0f);
    int ei = (int)ceilf(energy_t[g] * 256.0f);
    const float4 pv = *(const float4*)&pemb[(size_t)pi * H_ + lane * 4];
    const float4 ev = *(const float4*)&eemb[(size_t)ei * H_ + lane * 4];
    float4 o;
    o.x = xv0 + pv.x + ev.x;
    o.y = xv1 + pv.y + ev.y;
    o.z = xv2 + pv.z + ev.z;
    o.w = xv3 + pv.w + ev.w;
    *(float4*)&out0[(size_t)g * H_ + lane * 4] = o;
  }
}

// ------------------------------------------------------------------
// Fused 4-layer MLP + head for ALL THREE predictors in one dispatch.
// blocks [0,512): pitch  [512,1024): energy  [1024,1152): duration.
// Block = 256 threads (4 waves), 128 rows; each wave owns 32 rows ->
// no __syncthreads. __launch_bounds__(256,2) matches the LDS-capped
// occupancy (2 blocks/CU) so fragments stay in registers; B-fragment
// global loads are double-buffered (prefetch nt+1 during nt's MFMAs).
// ------------------------------------------------------------------
__global__ __launch_bounds__(256, 2) void predictor_kernel(
    const float* __restrict__ x,
    const half_t* __restrict__ Wp,
    const float* __restrict__ dur_b, const float* __restrict__ dur_w, const float* __restrict__ dur_b2,
    const float* __restrict__ pit_b, const float* __restrict__ pit_w, const float* __restrict__ pit_b2,
    const float* __restrict__ en_b,  const float* __restrict__ en_w,  const float* __restrict__ en_b2,
    const int* __restrict__ idx_ws, const int* __restrict__ mlw,
    const float* __restrict__ src_seq, const unsigned char* __restrict__ src_mask,
    float* __restrict__ out1, float* __restrict__ out2, float* __restrict__ out3) {
  __shared__ half_t hlds[128 * HST];
  int bid = blockIdx.x;
  int mode, blk;
  const half_t* W; const float* bias; const float* wh; const float* b2p; float* outp;
  if (bid < 512)       { mode = 1; blk = bid;        W = Wp + 262144; bias = pit_b; wh = pit_w; b2p = pit_b2; outp = out2; }
  else if (bid < 1024) { mode = 2; blk = bid - 512;  W = Wp + 524288; bias = en_b;  wh = en_w;  b2p = en_b2;  outp = out3; }
  else                 { mode = 0; blk = bid - 1024; W = Wp;          bias = dur_b; wh = dur_w; b2p = dur_b2; outp = out1; }

  int tid = threadIdx.x;
  int wv = tid >> 6, lane = tid & 63;
  int mi = lane & 15, qi = lane >> 4;
  int wrow0 = wv * 32;
  int brow0 = blk * 128;

  // ---- stage input rows (f16) into LDS; wave stages its own 32 rows ----
  if (mode == 0) {
    for (int it = 0; it < 32; ++it) {
      int row = brow0 + wrow0 + it;
      const float4 xv = *(const float4*)&x[(size_t)row * H_ + lane * 4];
      half_t* dst = &hlds[(wrow0 + it) * HST + lane * 4];
      dst[0] = (half_t)xv.x; dst[1] = (half_t)xv.y;
      dst[2] = (half_t)xv.z; dst[3] = (half_t)xv.w;
    }
  } else {
    int b = brow0 >> 11;       // 2048 rows per batch, 128 | 2048
    int m0 = brow0 & (L_ - 1);
    int ml = mlw[b];
    for (int it = 0; it < 32; ++it) {
      int m = m0 + wrow0 + it;
      float x0 = 0.f, x1 = 0.f, x2 = 0.f, x3 = 0.f;
      if (m < ml) {
        int ir = idx_ws[b * L_ + m];
        const float4 xv = *(const float4*)&x[((size_t)(b * T_ + ir)) * H_ + lane * 4];
        x0 = xv.x; x1 = xv.y; x2 = xv.z; x3 = xv.w;
      }
      half_t* dst = &hlds[(wrow0 + it) * HST + lane * 4];
      dst[0] = (half_t)x0; dst[1] = (half_t)x1;
      dst[2] = (half_t)x2; dst[3] = (half_t)x3;
    }
  }

  // ---- 4 layers: h = relu(h @ W + b), in-place per wave ----
  for (int layer = 0; layer < 4; ++layer) {
    half8 afr0[8], afr1[8];
#pragma unroll
    for (int kk = 0; kk < 8; ++kk) {
      afr0[kk] = *(const half8*)&hlds[(wrow0 + mi) * HST + kk * 32 + qi * 8];
      afr1[kk] = *(const half8*)&hlds[(wrow0 + 16 + mi) * HST + kk * 32 + qi * 8];
    }
    const half_t* wl = W + (size_t)layer * 65536;
    const float* bl = bias + layer * 256;
    half8 bA[8], bB[8];
#pragma unroll
    for (int kk = 0; kk < 8; ++kk)
      bA[kk] = *(const half8*)&wl[(size_t)(kk * 16 + 0) * 512 + lane * 8];
#pragma unroll 1
    for (int nt2 = 0; nt2 < 8; ++nt2) {
      int nt0 = nt2 * 2;
      // prefetch B-frags for nt0+1 while computing nt0
#pragma unroll
      for (int kk = 0; kk < 8; ++kk)
        bB[kk] = *(const half8*)&wl[(size_t)(kk * 16 + nt0 + 1) * 512 + lane * 8];
      {
        float bn = bl[nt0 * 16 + mi];
        floatx4 acc0 = {bn, bn, bn, bn};
        floatx4 acc1 = {bn, bn, bn, bn};
#pragma unroll
        for (int kk = 0; kk < 8; ++kk) {
          acc0 = __builtin_amdgcn_mfma_f32_16x16x32_f16(afr0[kk], bA[kk], acc0, 0, 0, 0);
          acc1 = __builtin_amdgcn_mfma_f32_16x16x32_f16(afr1[kk], bA[kk], acc1, 0, 0, 0);
        }
#pragma unroll
        for (int r = 0; r < 4; ++r) {
          float v0 = fmaxf(acc0[r], 0.f);
          float v1 = fmaxf(acc1[r], 0.f);
          hlds[(wrow0 + qi * 4 + r) * HST + nt0 * 16 + mi] = (half_t)v0;
          hlds[(wrow0 + 16 + qi * 4 + r) * HST + nt0 * 16 + mi] = (half_t)v1;
        }
      }
      // prefetch B-frags for nt0+2 while computing nt0+1
      if (nt2 < 7) {
#pragma unroll
        for (int kk = 0; kk < 8; ++kk)
          bA[kk] = *(const half8*)&wl[(size_t)(kk * 16 + nt0 + 2) * 512 + lane * 8];
      }
      {
        float bn = bl[(nt0 + 1) * 16 + mi];
        floatx4 acc0 = {bn, bn, bn, bn};
        floatx4 acc1 = {bn, bn, bn, bn};
#pragma unroll
        for (int kk = 0; kk < 8; ++kk) {
          acc0 = __builtin_amdgcn_mfma_f32_16x16x32_f16(afr0[kk], bB[kk], acc0, 0, 0, 0);
          acc1 = __builtin_amdgcn_mfma_f32_16x16x32_f16(afr1[kk], bB[kk], acc1, 0, 0, 0);
        }
#pragma unroll
        for (int r = 0; r < 4; ++r) {
          float v0 = fmaxf(acc0[r], 0.f);
          float v1 = fmaxf(acc1[r], 0.f);
          hlds[(wrow0 + qi * 4 + r) * HST + (nt0 + 1) * 16 + mi] = (half_t)v0;
          hlds[(wrow0 + 16 + qi * 4 + r) * HST + (nt0 + 1) * 16 + mi] = (half_t)v1;
        }
      }
    }
  }

  // ---- head: out = h . w + b2, then per-mode epilogue ----
  {
    int r = lane >> 1, hf = lane & 1;
    int lrow = wrow0 + r;
    float sum = 0.f;
    const half_t* hrow = &hlds[lrow * HST + hf * 128];
    const float* whp = wh + hf * 128;
#pragma unroll
    for (int j = 0; j < 16; ++j) {
      half8 hv = *(const half8*)&hrow[j * 8];
#pragma unroll
      for (int u = 0; u < 8; ++u) sum += (float)hv[u] * whp[j * 8 + u];
    }
    sum += __shfl_xor(sum, 1);
    if (hf == 0) {
      int row = brow0 + lrow;
      float d = sum + b2p[0];
      if (mode == 0) {
        if (src_mask[row]) d = 0.f;
        float s2 = src_seq[(size_t)row * 3 + 2];
        outp[row] = (tanhf(d) + 1.0f) * s2;
      } else {
        int b = row >> 11;
        int m = row & (L_ - 1);
        float v = (m >= mlw[b]) ? 0.f : d;
        outp[row] = (mode == 1) ? fmaxf(v, 0.f) : v;
      }
    }
  }
}

extern "C" void kernel_launch(void* const* d_in, const int* in_sizes, int n_in,
                              void* d_out, int out_size, void* d_ws, size_t ws_size,
                              hipStream_t stream) {
  const float* x        = (const float*)d_in[0];
  const float* src_seq  = (const float*)d_in[1];
  const int*   durt     = (const int*)d_in[2];
  const float* pitcht   = (const float*)d_in[3];
  const float* energyt  = (const float*)d_in[4];
  const unsigned char* src_mask = (const unsigned char*)d_in[5];
  const float* dur_W  = (const float*)d_in[7];
  const float* dur_b  = (const float*)d_in[8];
  const float* dur_w  = (const float*)d_in[9];
  const float* dur_b2 = (const float*)d_in[10];
  const float* pit_W  = (const float*)d_in[11];
  const float* pit_b  = (const float*)d_in[12];
  const float* pit_w  = (const float*)d_in[13];
  const float* pit_b2 = (const float*)d_in[14];
  const float* en_W   = (const float*)d_in[15];
  const float* en_b   = (const float*)d_in[16];
  const float* en_w   = (const float*)d_in[17];
  const float* en_b2  = (const float*)d_in[18];
  const float* pemb   = (const float*)d_in[19];
  const float* eemb   = (const float*)d_in[20];

  float* out0 = (float*)d_out;              // [32,2048,256]
  float* out1 = out0 + 16777216;            // [32,512]   log_duration
  float* out2 = out1 + 16384;               // [32,2048]  pitch_prediction
  float* out3 = out2 + 65536;               // [32,2048]  energy_prediction
  float* out4 = out3 + 65536;               // [32]       mel_len (as float)
  float* out5 = out4 + 32;                  // [32,2048]  mel_mask (0/1 float)

  int* idx_ws = (int*)d_ws;                 // 65536 ints
  int* ml_ws  = idx_ws + 65536;             // 32 ints
  half_t* Wp  = (half_t*)((char*)d_ws + 262272);  // 786432 halves, 16B aligned

  prep_weights_kernel<<<dim3(384), dim3(256), 0, stream>>>(dur_W, pit_W, en_W, Wp);
  regulate_kernel<<<dim3(512), dim3(256), 0, stream>>>(x, durt, pitcht, energyt, pemb, eemb,
                                                       idx_ws, ml_ws, out0, out4, out5);
  predictor_kernel<<<dim3(1152), dim3(256), 0, stream>>>(
      x, Wp,
      dur_b, dur_w, dur_b2,
      pit_b, pit_w, pit_b2,
      en_b, en_w, en_b2,
      idx_ws, ml_ws, src_seq, src_mask,
      out1, out2, out3);
}

// Round 3
// 275.310 us; speedup vs baseline: 1.3970x; 1.0269x over previous
//
#include <hip/hip_runtime.h>

typedef _Float16 half_t;
typedef _Float16 half4 __attribute__((ext_vector_type(4)));
typedef _Float16 half8 __attribute__((ext_vector_type(8)));
typedef float floatx4 __attribute__((ext_vector_type(4)));

#define HST 264            // LDS row stride in halves: 256 + 8 pad (16B, odd multiple of 16B)
#define B_ 32
#define T_ 512
#define H_ 256
#define L_ 2048

// ------------------------------------------------------------------
// Weight prep: fp32 [pred][layer][k][n] -> f16 MFMA fragment layout.
// Frag id t = ((pred*4+layer)*8 + kk)*16 + nt ; lane l holds 8 halves:
//   W[kk*32 + (l>>4)*8 + j][nt*16 + (l&15)]
// (serves as A-operand layout for the swapped D=W^T*h^T formulation)
// ------------------------------------------------------------------
__global__ void prep_weights_kernel(const float* __restrict__ dur_W,
                                    const float* __restrict__ pit_W,
                                    const float* __restrict__ en_W,
                                    half_t* __restrict__ Wp) {
  int g = blockIdx.x * 256 + threadIdx.x;   // [0, 98304)
  int lane = g & 63;
  int t = g >> 6;                           // [0, 1536)
  int nt = t & 15;
  int kk = (t >> 4) & 7;
  int layer = (t >> 7) & 3;
  int pred = t >> 9;
  const float* W = (pred == 0 ? dur_W : (pred == 1 ? pit_W : en_W)) + layer * 65536;
  int n = nt * 16 + (lane & 15);
  int k0 = kk * 32 + (lane >> 4) * 8;
  half8 o;
#pragma unroll
  for (int j = 0; j < 8; ++j) o[j] = (half_t)W[(k0 + j) * 256 + n];
  *(half8*)&Wp[(size_t)t * 512 + lane * 8] = o;
}

// ------------------------------------------------------------------
// Meta: per-batch scan of durations, searchsorted idx, pitch/energy
// bucket indices, mel_len (out4) and mel_mask (out5). 32 blocks x 256.
// ------------------------------------------------------------------
__global__ void meta_kernel(const int* __restrict__ dur,
                            const float* __restrict__ pitch_t,
                            const float* __restrict__ energy_t,
                            int* __restrict__ idx_ws,
                            int* __restrict__ pi_ws,
                            int* __restrict__ ei_ws,
                            int* __restrict__ ml_ws,
                            float* __restrict__ out4,
                            float* __restrict__ out5) {
  __shared__ int cum_l[T_];
  __shared__ int ml_s;
  int b = blockIdx.x;
  int tid = threadIdx.x;
  if (tid < 64) {
    int l = tid;
    const int* dr = dur + b * T_;
    int v[8];
    int base = l * 8;
#pragma unroll
    for (int j = 0; j < 8; ++j) v[j] = dr[base + j];
#pragma unroll
    for (int j = 1; j < 8; ++j) v[j] += v[j - 1];
    int tot = v[7];
    int inc = tot;
    for (int d = 1; d < 64; d <<= 1) {
      int t = __shfl_up(inc, d);
      if (l >= d) inc += t;
    }
    int excl = inc - tot;
#pragma unroll
    for (int j = 0; j < 8; ++j) cum_l[base + j] = excl + v[j];
    if (l == 63) {
      int mel = min(inc, L_);
      ml_s = mel;
      ml_ws[b] = mel;
      out4[b] = (float)mel;
    }
  }
  __syncthreads();
  int ml = ml_s;
#pragma unroll
  for (int j = 0; j < 8; ++j) {
    int m = j * 256 + tid;
    int lo = 0;
#pragma unroll
    for (int sh = 8; sh >= 0; --sh) {
      int c = lo + (1 << sh);
      if (c <= T_ && cum_l[c - 1] <= m) lo = c;
    }
    int idx = min(lo, T_ - 1);
    int g = b * L_ + m;
    idx_ws[g] = idx;
    pi_ws[g] = (int)ceilf(pitch_t[g] * 256.0f);
    ei_ws[g] = (int)ceilf(energy_t[g] * 256.0f);
    out5[g] = (m >= ml) ? 1.0f : 0.0f;
  }
}

// ------------------------------------------------------------------
// out0 = gather(x, idx) * inbounds + pemb[pi] + eemb[ei].
// One frame per wave, 4 waves/block, 16384 blocks -> latency fully hidden.
// ------------------------------------------------------------------
__global__ void out0_kernel(const float* __restrict__ x,
                            const float* __restrict__ pemb,
                            const float* __restrict__ eemb,
                            const int* __restrict__ idx_ws,
                            const int* __restrict__ pi_ws,
                            const int* __restrict__ ei_ws,
                            const int* __restrict__ ml_ws,
                            float* __restrict__ out0) {
  int wid = blockIdx.x * 4 + (threadIdx.x >> 6);   // frame id [0, 65536)
  int lane = threadIdx.x & 63;
  int b = wid >> 11;
  int m = wid & (L_ - 1);
  int ml = ml_ws[b];
  int ir = idx_ws[wid];
  int pi = pi_ws[wid];
  int ei = ei_ws[wid];
  float4 xv = {0.f, 0.f, 0.f, 0.f};
  if (m < ml) xv = *(const float4*)&x[((size_t)(b * T_ + ir)) * H_ + lane * 4];
  const float4 pv = *(const float4*)&pemb[(size_t)pi * H_ + lane * 4];
  const float4 ev = *(const float4*)&eemb[(size_t)ei * H_ + lane * 4];
  float4 o;
  o.x = xv.x + pv.x + ev.x;
  o.y = xv.y + pv.y + ev.y;
  o.z = xv.z + pv.z + ev.z;
  o.w = xv.w + pv.w + ev.w;
  *(float4*)&out0[(size_t)wid * H_ + lane * 4] = o;
}

// ------------------------------------------------------------------
// Fused 4-layer MLP + head, all three predictors in one dispatch.
// blocks [0,512): pitch  [512,1024): energy  [1024,1152): duration.
// Block = 128 threads (2 waves) owning 128 rows. Waves SPLIT N
// (wave w computes nt = w*8 .. w*8+7), so the block reads each layer's
// 128KB weight matrix ONCE -> 4x less L2 traffic than 32-rows/wave.
// All 128 rows' h fragments are register-resident (64 x half8).
// Swapped MFMA operands (A=W, B=h) make D[n][m]: lane holds 4
// consecutive features of one token -> packed b64 LDS writes.
// LDS 67.5KB caps occupancy at 1 wave/SIMD, so large VGPR use is free.
// ------------------------------------------------------------------
__global__ __launch_bounds__(128, 1) void predictor_kernel(
    const float* __restrict__ x,
    const half_t* __restrict__ Wp,
    const float* __restrict__ dur_b, const float* __restrict__ dur_w, const float* __restrict__ dur_b2,
    const float* __restrict__ pit_b, const float* __restrict__ pit_w, const float* __restrict__ pit_b2,
    const float* __restrict__ en_b,  const float* __restrict__ en_w,  const float* __restrict__ en_b2,
    const int* __restrict__ idx_ws, const int* __restrict__ mlw,
    const float* __restrict__ src_seq, const unsigned char* __restrict__ src_mask,
    float* __restrict__ out1, float* __restrict__ out2, float* __restrict__ out3) {
  __shared__ half_t hlds[128 * HST];
  int bid = blockIdx.x;
  int mode, blk;
  const half_t* W; const float* bias; const float* wh; const float* b2p; float* outp;
  if (bid < 512)       { mode = 1; blk = bid;        W = Wp + 262144; bias = pit_b; wh = pit_w; b2p = pit_b2; outp = out2; }
  else if (bid < 1024) { mode = 2; blk = bid - 512;  W = Wp + 524288; bias = en_b;  wh = en_w;  b2p = en_b2;  outp = out3; }
  else                 { mode = 0; blk = bid - 1024; W = Wp;          bias = dur_b; wh = dur_w; b2p = dur_b2; outp = out1; }

  int tid = threadIdx.x;
  int wv = tid >> 6, lane = tid & 63;
  int mi = lane & 15, qi = lane >> 4;
  int brow0 = blk * 128;

  // ---- stage input rows (f16) into LDS; wave stages rows wv*64..+63 ----
  if (mode == 0) {
    for (int it = 0; it < 64; ++it) {
      int rl = wv * 64 + it;
      const float4 xv = *(const float4*)&x[(size_t)(brow0 + rl) * H_ + lane * 4];
      half4 h4;
      h4[0] = (half_t)xv.x; h4[1] = (half_t)xv.y;
      h4[2] = (half_t)xv.z; h4[3] = (half_t)xv.w;
      *(half4*)&hlds[rl * HST + lane * 4] = h4;
    }
  } else {
    int b = brow0 >> 11;       // 2048 rows per batch, 128 | 2048
    int m0 = brow0 & (L_ - 1);
    int ml = mlw[b];
    for (int it = 0; it < 64; ++it) {
      int rl = wv * 64 + it;
      int m = m0 + rl;
      float4 xv = {0.f, 0.f, 0.f, 0.f};
      if (m < ml) {
        int ir = idx_ws[b * L_ + m];
        xv = *(const float4*)&x[((size_t)(b * T_ + ir)) * H_ + lane * 4];
      }
      half4 h4;
      h4[0] = (half_t)xv.x; h4[1] = (half_t)xv.y;
      h4[2] = (half_t)xv.z; h4[3] = (half_t)xv.w;
      *(half4*)&hlds[rl * HST + lane * 4] = h4;
    }
  }
  __syncthreads();

  // ---- 4 layers: h = relu(h @ W + b) ----
  int nt0 = wv * 8;
#pragma unroll 1
  for (int layer = 0; layer < 4; ++layer) {
    // read ALL 128 rows' fragments into registers (B-operand layout)
    half8 hf[8][8];   // [mt][kk] : h[mt*16+mi][kk*32+qi*8 .. +7]
#pragma unroll
    for (int mt = 0; mt < 8; ++mt)
#pragma unroll
      for (int kk = 0; kk < 8; ++kk)
        hf[mt][kk] = *(const half8*)&hlds[(mt * 16 + mi) * HST + kk * 32 + qi * 8];
    __syncthreads();   // all reads done before anyone writes this layer

    const half_t* wl = W + (size_t)layer * 65536;
    const float* bl = bias + layer * 256;
    half8 wbuf[2][8];
    float4 bbuf[2];
#pragma unroll
    for (int kk = 0; kk < 8; ++kk)
      wbuf[0][kk] = *(const half8*)&wl[(size_t)(kk * 16 + nt0) * 512 + lane * 8];
    bbuf[0] = *(const float4*)&bl[nt0 * 16 + qi * 4];

#pragma unroll
    for (int ntl = 0; ntl < 8; ++ntl) {
      int cur = ntl & 1, nxt = cur ^ 1;
      if (ntl < 7) {
#pragma unroll
        for (int kk = 0; kk < 8; ++kk)
          wbuf[nxt][kk] = *(const half8*)&wl[(size_t)(kk * 16 + nt0 + ntl + 1) * 512 + lane * 8];
        bbuf[nxt] = *(const float4*)&bl[(nt0 + ntl + 1) * 16 + qi * 4];
      }
      floatx4 acc[8];
#pragma unroll
      for (int mt = 0; mt < 8; ++mt)
        acc[mt] = (floatx4){bbuf[cur].x, bbuf[cur].y, bbuf[cur].z, bbuf[cur].w};
#pragma unroll
      for (int kk = 0; kk < 8; ++kk)
#pragma unroll
        for (int mt = 0; mt < 8; ++mt)
          acc[mt] = __builtin_amdgcn_mfma_f32_16x16x32_f16(wbuf[cur][kk], hf[mt][kk], acc[mt], 0, 0, 0);
      int colbase = (nt0 + ntl) * 16 + qi * 4;
#pragma unroll
      for (int mt = 0; mt < 8; ++mt) {
        half4 h4;
        h4[0] = (half_t)fmaxf(acc[mt][0], 0.f);
        h4[1] = (half_t)fmaxf(acc[mt][1], 0.f);
        h4[2] = (half_t)fmaxf(acc[mt][2], 0.f);
        h4[3] = (half_t)fmaxf(acc[mt][3], 0.f);
        *(half4*)&hlds[(mt * 16 + mi) * HST + colbase] = h4;
      }
    }
    __syncthreads();   // writes done before next layer's reads / head
  }

  // ---- head: out = h . w + b2, per-mode epilogue. 1 lane = 1 row ----
  {
    int rl = wv * 64 + lane;
    float sum = 0.f;
    const half_t* hrow = &hlds[rl * HST];
#pragma unroll
    for (int j = 0; j < 32; ++j) {
      half8 hv = *(const half8*)&hrow[j * 8];
#pragma unroll
      for (int u = 0; u < 8; ++u) sum += (float)hv[u] * wh[j * 8 + u];
    }
    int row = brow0 + rl;
    float d = sum + b2p[0];
    if (mode == 0) {
      if (src_mask[row]) d = 0.f;
      float s2 = src_seq[(size_t)row * 3 + 2];
      outp[row] = (tanhf(d) + 1.0f) * s2;
    } else {
      int b = row >> 11;
      int m = row & (L_ - 1);
      float v = (m >= mlw[b]) ? 0.f : d;
      outp[row] = (mode == 1) ? fmaxf(v, 0.f) : v;
    }
  }
}

extern "C" void kernel_launch(void* const* d_in, const int* in_sizes, int n_in,
                              void* d_out, int out_size, void* d_ws, size_t ws_size,
                              hipStream_t stream) {
  const float* x        = (const float*)d_in[0];
  const float* src_seq  = (const float*)d_in[1];
  const int*   durt     = (const int*)d_in[2];
  const float* pitcht   = (const float*)d_in[3];
  const float* energyt  = (const float*)d_in[4];
  const unsigned char* src_mask = (const unsigned char*)d_in[5];
  const float* dur_W  = (const float*)d_in[7];
  const float* dur_b  = (const float*)d_in[8];
  const float* dur_w  = (const float*)d_in[9];
  const float* dur_b2 = (const float*)d_in[10];
  const float* pit_W  = (const float*)d_in[11];
  const float* pit_b  = (const float*)d_in[12];
  const float* pit_w  = (const float*)d_in[13];
  const float* pit_b2 = (const float*)d_in[14];
  const float* en_W   = (const float*)d_in[15];
  const float* en_b   = (const float*)d_in[16];
  const float* en_w   = (const float*)d_in[17];
  const float* en_b2  = (const float*)d_in[18];
  const float* pemb   = (const float*)d_in[19];
  const float* eemb   = (const float*)d_in[20];

  float* out0 = (float*)d_out;              // [32,2048,256]
  float* out1 = out0 + 16777216;            // [32,512]   log_duration
  float* out2 = out1 + 16384;               // [32,2048]  pitch_prediction
  float* out3 = out2 + 65536;               // [32,2048]  energy_prediction
  float* out4 = out3 + 65536;               // [32]       mel_len (as float)
  float* out5 = out4 + 32;                  // [32,2048]  mel_mask (0/1 float)

  int* idx_ws = (int*)d_ws;                 // 65536 ints
  int* pi_ws  = idx_ws + 65536;             // 65536 ints
  int* ei_ws  = pi_ws + 65536;              // 65536 ints
  int* ml_ws  = ei_ws + 65536;              // 32 ints
  half_t* Wp  = (half_t*)((char*)d_ws + 786560);  // 786432 halves, 16B aligned

  prep_weights_kernel<<<dim3(384), dim3(256), 0, stream>>>(dur_W, pit_W, en_W, Wp);
  meta_kernel<<<dim3(32), dim3(256), 0, stream>>>(durt, pitcht, energyt,
                                                  idx_ws, pi_ws, ei_ws, ml_ws, out4, out5);
  out0_kernel<<<dim3(16384), dim3(256), 0, stream>>>(x, pemb, eemb,
                                                     idx_ws, pi_ws, ei_ws, ml_ws, out0);
  predictor_kernel<<<dim3(1152), dim3(128), 0, stream>>>(
      x, Wp,
      dur_b, dur_w, dur_b2,
      pit_b, pit_w, pit_b2,
      en_b, en_w, en_b2,
      idx_ws, ml_ws, src_seq, src_mask,
      out1, out2, out3);
}